// Round 10
// baseline (507.546 us; speedup 1.0000x reference)
//
#include <hip/hip_runtime.h>

// Gemma2 attention, S=4096 HID=2048 NH=8 NKV=4 HD=256, causal, tanh softcap 50,
// scaling 1/16. R15: fold combine into gemm2. combine only merged PA/PB ->
// attn rows>=2048, which gemm2 re-read immediately. gemm_out (m97 structure,
// f32 out) now: blocks with m0>=2048 (tile-aligned, block-uniform) reg-stage
// A = (PA+PB)*1/(lA+lB) -> bf16 -> ds_write_b128 into the same LDS slot;
// h = kt>>8 is k-tile-uniform so p=pi*8+h and la/lb are cheap per-tile
// scalars. Removes 1 launch+tail, 16MB attn round-trip, 40MB combine traffic.
// flash = R14 (validated 164us: split-stage vmcnt(8) K-first), gemm1 =
// gemm_mn (R13), prep1/prep2 fused (R13).

#define SEQ 4096
#define HIDDEN 2048
#define NHEADS 8
#define HDIM 256

typedef unsigned short u16;
typedef __attribute__((ext_vector_type(8))) __bf16 bf16x8;
typedef __attribute__((ext_vector_type(4))) float f32x4;
typedef __attribute__((ext_vector_type(16))) float f32x16;

static __device__ inline u16 f2bf(float f) {
  union { float f; unsigned u; } x; x.f = f;
  unsigned r = x.u + 0x7FFFu + ((x.u >> 16) & 1u);   // RNE
  return (u16)(r >> 16);
}
static __device__ inline float bf2f(u16 u) {
  union { unsigned u; float f; } x; x.u = ((unsigned)u) << 16;
  return x.f;
}

typedef __attribute__((address_space(1))) const unsigned int* gp_t;
typedef __attribute__((address_space(3))) unsigned int* lp_t;
static __device__ inline void load_lds16(const u16* g, u16* l) {
  __builtin_amdgcn_global_load_lds((gp_t)g, (lp_t)l, 16, 0, 0);
}

#define BARX() do { __builtin_amdgcn_s_barrier(); asm volatile("" ::: "memory"); } while (0)

// ---------------- prep1: convert_hs + 4x transpose_w fused ----------------

__global__ void prep1_kernel(const float* __restrict__ hs, u16* __restrict__ hsb,
                             const float* __restrict__ wq, const float* __restrict__ wk,
                             const float* __restrict__ wv, const float* __restrict__ wo,
                             u16* __restrict__ wqkvT, u16* __restrict__ woT) {
  __shared__ u16 tile[64][65];
  int bid = blockIdx.x, tid = threadIdx.x;
  if (bid < 8192) {                            // convert hs -> bf16
    int i = bid * 256 + tid;
    float4 v = ((const float4*)hs)[i];
    ushort4 o;
    o.x = f2bf(v.x); o.y = f2bf(v.y); o.z = f2bf(v.z); o.w = f2bf(v.w);
    ((ushort4*)hsb)[i] = o;
    return;
  }
  int tb = bid - 8192;
  const float* src; u16* dst; int N, n0, k0;
  if (tb < 1024)      { src = wq; dst = wqkvT;                        N = 2048; n0 = (tb & 31) * 64; k0 = (tb >> 5) * 64; }
  else if (tb < 1536) { int x = tb - 1024; src = wk; dst = wqkvT + (size_t)2048 * 2048; N = 1024; n0 = (x & 15) * 64; k0 = (x >> 4) * 64; }
  else if (tb < 2048) { int x = tb - 1536; src = wv; dst = wqkvT + (size_t)3072 * 2048; N = 1024; n0 = (x & 15) * 64; k0 = (x >> 4) * 64; }
  else                { int x = tb - 2048; src = wo; dst = woT;       N = 2048; n0 = (x & 31) * 64; k0 = (x >> 5) * 64; }
  const int K = 2048;
  for (int i = 0; i < 16; i++) {
    int idx = i * 256 + tid; int r = idx >> 6, c = idx & 63;
    tile[r][c] = f2bf(src[(size_t)(k0 + r) * N + n0 + c]);
  }
  __syncthreads();
  for (int i = 0; i < 16; i++) {
    int idx = i * 256 + tid; int r = idx >> 6, c = idx & 63;
    dst[(size_t)(n0 + r) * K + k0 + c] = tile[c][r];
  }
}

// ---------------- prep2: rope + transpose_v fused ----------------

__global__ void prep2_kernel(u16* __restrict__ qkv, u16* __restrict__ vT) {
  __shared__ u16 tile[64][65];
  int bid = blockIdx.x, tid = threadIdx.x;
  if (bid < 2048) {                            // rope: one sincos per (s,i)
    int idx = bid * 256 + tid;                 // 4096*128
    int s = idx >> 7;
    int i = idx & 127;
    float inv = __expf(-(float)i * 0.0719557841560639f);  // ln(10000)/128
    float ang = (float)s * inv;
    float sn, cs;
    sincosf(ang, &sn, &cs);
    size_t rowb = (size_t)s * 4096;
#pragma unroll
    for (int hh = 0; hh < 12; hh++) {
      size_t base = rowb + hh * 256 + i;
      float a = bf2f(qkv[base]);
      float b = bf2f(qkv[base + 128]);
      qkv[base]       = f2bf(a * cs - b * sn);
      qkv[base + 128] = f2bf(b * cs + a * sn);
    }
    return;
  }
  int x = bid - 2048;
  int d0 = (x & 15) * 64, s0 = (x >> 4) * 64;
  for (int i = 0; i < 16; i++) {
    int idx = i * 256 + tid; int r = idx >> 6, c = idx & 63;
    tile[r][c] = qkv[(size_t)(s0 + r) * 4096 + 3072 + d0 + c];
  }
  __syncthreads();
  for (int i = 0; i < 16; i++) {
    int idx = i * 256 + tid; int r = idx >> 6, c = idx & 63;
    vT[(size_t)(d0 + r) * 4096 + s0 + c] = tile[c][r];
  }
}

// ---------------- gemm1: 256x128 tile, BK=32, ring-2, 2 blocks/CU ----------------

__global__ __launch_bounds__(512, 4) void gemm_mn_kernel(
    const u16* __restrict__ A, const u16* __restrict__ Bt, u16* __restrict__ C,
    int M, int N, int K) {
  __shared__ __attribute__((aligned(16))) u16 As[2][256 * 32];
  __shared__ __attribute__((aligned(16))) u16 Bs[2][128 * 32];
  int tid = threadIdx.x;
  int wid = tid >> 6, lane = tid & 63;
  int lm = lane & 15, kq = lane >> 4;
  int wm = (wid >> 1) * 64, wn = (wid & 1) * 64;
  int m0 = blockIdx.y * 256, n0 = blockIdx.x * 128;
  int T = K >> 5;

  int r0 = tid >> 2, c0 = tid & 3;
  int csw = ((c0 ^ (r0 & 3)) << 3);
  const u16* gA0 = A  + (size_t)(m0 + r0) * K + csw;
  const u16* gA1 = A  + (size_t)(m0 + 128 + r0) * K + csw;
  const u16* gB0 = Bt + (size_t)(n0 + r0) * K + csw;

  f32x4 acc[4][4];
#pragma unroll
  for (int a = 0; a < 4; a++)
#pragma unroll
    for (int b = 0; b < 4; b++) acc[a][b] = (f32x4){0.f, 0.f, 0.f, 0.f};

  int xsw = ((kq ^ (lm & 3)) << 3);

  load_lds16(gA0, &As[0][tid * 8]);
  load_lds16(gA1, &As[0][(512 + tid) * 8]);
  load_lds16(gB0, &Bs[0][tid * 8]);
  asm volatile("s_waitcnt vmcnt(0)" ::: "memory");
  BARX();

  for (int t = 0; t < T; ++t) {
    int cur = t & 1;
    if (t + 1 < T) {
      int nb = 1 - cur;
      load_lds16(gA0 + (t + 1) * 32, &As[nb][tid * 8]);
      load_lds16(gA1 + (t + 1) * 32, &As[nb][(512 + tid) * 8]);
      load_lds16(gB0 + (t + 1) * 32, &Bs[nb][tid * 8]);
    }
    bf16x8 af[4], bfr[4];
#pragma unroll
    for (int f = 0; f < 4; f++)
      af[f] = *(const bf16x8*)&As[cur][(wm + f * 16 + lm) * 32 + xsw];
#pragma unroll
    for (int f = 0; f < 4; f++)
      bfr[f] = *(const bf16x8*)&Bs[cur][(wn + f * 16 + lm) * 32 + xsw];
    __builtin_amdgcn_s_setprio(1);
#pragma unroll
    for (int mi = 0; mi < 4; mi++)
#pragma unroll
      for (int ni = 0; ni < 4; ni++)
        acc[mi][ni] = __builtin_amdgcn_mfma_f32_16x16x32_bf16(af[mi], bfr[ni],
                                                             acc[mi][ni], 0, 0, 0);
    __builtin_amdgcn_s_setprio(0);
    if (t + 1 < T) {
      asm volatile("s_waitcnt vmcnt(0)" ::: "memory");
      BARX();
    }
  }

#pragma unroll
  for (int mi = 0; mi < 4; mi++) {
    int row = m0 + wm + mi * 16 + kq * 4;
#pragma unroll
    for (int ni = 0; ni < 4; ni++) {
      int col = n0 + wn + ni * 16 + lm;
#pragma unroll
      for (int r = 0; r < 4; r++)
        C[(size_t)(row + r) * N + col] = f2bf(acc[mi][ni][r]);
    }
  }
}

// ---------------- gemm2 + combine fold: out = attn_merged * woT^T ----------------
// m97 structure, f32 out. Blocks with m0>=2048 (block-uniform) reg-stage A
// from PA/PB partials: val = (PA+PB) * 1/(lA+lB), bf16-packed, ds_write_b128
// to the same LDS slot the fast path fills. h = kt>>8 is uniform per k-tile
// (scol<=56 never crosses the 256-col head boundary). p = pi*8+h matches
// flash's pair index r.

__global__ __launch_bounds__(256, 2) void gemm_out_kernel(
    const u16* __restrict__ A, const u16* __restrict__ Bt, float* __restrict__ Cout,
    const float* __restrict__ PA, const float* __restrict__ PB,
    const float* __restrict__ lbuf, int M, int N, int K) {
  __shared__ __attribute__((aligned(16))) u16 As[128 * 64];
  __shared__ __attribute__((aligned(16))) u16 Bs[128 * 64];
  int tid = threadIdx.x;
  int wave = tid >> 6, lane = tid & 63;
  int lm = lane & 15, qd = lane >> 4;
  int m0 = blockIdx.y * 128, n0 = blockIdx.x * 128;
  int wm = (wave >> 1) * 64, wn = (wave & 1) * 64;
  bool slow = (m0 >= 2048);                    // rows from PA/PB partials

  f32x4 acc[4][4];
#pragma unroll
  for (int a = 0; a < 4; a++)
#pragma unroll
    for (int b = 0; b < 4; b++) acc[a][b] = (f32x4){0.f, 0.f, 0.f, 0.f};

  int srow = lane >> 3;
  int scol = (lane & 7) * 8;

  for (int kt = 0; kt < K; kt += 64) {
    __syncthreads();
    if (!slow) {
#pragma unroll
      for (int t = 0; t < 4; t++) {
        int j = wave * 4 + t;
        int row = j * 8 + srow;
        load_lds16(A  + (size_t)(m0 + row) * K + kt + scol, As + j * 512);
        load_lds16(Bt + (size_t)(n0 + row) * K + kt + scol, Bs + j * 512);
      }
    } else {
      int h = kt >> 8;                         // head, uniform this k-tile
      int dk = (kt & 255) + scol;              // d offset within head (<=248)
#pragma unroll
      for (int t = 0; t < 4; t++) {
        int j = wave * 4 + t;
        int row = j * 8 + srow;
        int m = m0 + row;
        int qt2 = m >> 6;
        int p = (63 - qt2) * 8 + h;            // flash pair index r
        int rw = m & 63;
        float la = lbuf[(size_t)(p * 16) * 2048 + 1536 + rw];
        float lb = lbuf[(size_t)(p * 16 + 1) * 2048 + 1536 + rw];
        float inv = 1.f / (la + lb);
        size_t src = ((size_t)p * 64 + rw) * 256 + dk;
        float4 a0 = *(const float4*)&PA[src];
        float4 a1 = *(const float4*)&PA[src + 4];
        float4 b0 = *(const float4*)&PB[src];
        float4 b1 = *(const float4*)&PB[src + 4];
        union { u16 q[8]; uint4 v; } pk_;
        pk_.q[0] = f2bf((a0.x + b0.x) * inv);
        pk_.q[1] = f2bf((a0.y + b0.y) * inv);
        pk_.q[2] = f2bf((a0.z + b0.z) * inv);
        pk_.q[3] = f2bf((a0.w + b0.w) * inv);
        pk_.q[4] = f2bf((a1.x + b1.x) * inv);
        pk_.q[5] = f2bf((a1.y + b1.y) * inv);
        pk_.q[6] = f2bf((a1.z + b1.z) * inv);
        pk_.q[7] = f2bf((a1.w + b1.w) * inv);
        *(uint4*)&As[j * 512 + lane * 8] = pk_.v;   // ds_write_b128, same slot
        load_lds16(Bt + (size_t)(n0 + row) * K + kt + scol, Bs + j * 512);
      }
    }
    __syncthreads();
#pragma unroll
    for (int kk = 0; kk < 2; kk++) {
      bf16x8 af[4], bfr[4];
#pragma unroll
      for (int mi = 0; mi < 4; mi++)
        af[mi] = *(const bf16x8*)&As[(wm + mi * 16 + lm) * 64 + kk * 32 + qd * 8];
#pragma unroll
      for (int ni = 0; ni < 4; ni++)
        bfr[ni] = *(const bf16x8*)&Bs[(wn + ni * 16 + lm) * 64 + kk * 32 + qd * 8];
#pragma unroll
      for (int mi = 0; mi < 4; mi++)
#pragma unroll
        for (int ni = 0; ni < 4; ni++)
          acc[mi][ni] = __builtin_amdgcn_mfma_f32_16x16x32_bf16(af[mi], bfr[ni],
                                                               acc[mi][ni], 0, 0, 0);
    }
  }
#pragma unroll
  for (int mi = 0; mi < 4; mi++) {
    int row = m0 + wm + mi * 16 + qd * 4;
#pragma unroll
    for (int ni = 0; ni < 4; ni++) {
      int col = n0 + wn + ni * 16 + lm;
#pragma unroll
      for (int r = 0; r < 4; r++)
        Cout[(size_t)(row + r) * N + col] = acc[mi][ni][r];
    }
  }
}

// ---------------- flash attention (R14: balanced 2 blocks/CU, split-stage vmcnt) ----------------

__global__ __launch_bounds__(256, 2) void flash_kernel(
    const u16* __restrict__ qkv, const u16* __restrict__ vT,
    u16* __restrict__ attn, float* __restrict__ PA, float* __restrict__ PB,
    float* __restrict__ lbuf /* == (float*)qkv base */) {
  __shared__ __attribute__((aligned(16))) u16 Ks[64 * 256];
  __shared__ __attribute__((aligned(16))) u16 Vs[256 * 64];
  __shared__ __attribute__((aligned(16))) u16 Pl[64 * 64];

  int tid = threadIdx.x;
  int w = tid >> 6, lane = tid & 63;
  int l31 = lane & 31, hi = lane >> 5;
  int qhalf = w >> 1, kh = w & 1, dhalf = w & 1;

  int b = blockIdx.x;            // 0..511
  int r = b & 255;
  int h = r & 7;                 // one head per XCD; same for b and b+256
  int pi = r >> 3;               // 0..31
  int kvh = h >> 1;
  int isA = (b < 256);
  int nseg = isA ? 2 : 1;

  int vlc = (lane & 7) ^ ((lane >> 3) & 7);    // V logical 16B chunk
  int vro = lane >> 3;                          // V row offset in 8-row window

  const u16* Kg  = qkv + 2048 + (size_t)kvh * 256;
  const u16* Vg0 = vT + (size_t)(kvh * 256) * 4096;

  bf16x8 ones;
#pragma unroll
  for (int e = 0; e < 8; e++) ones[e] = (__bf16)1.0f;

  for (int si = 0; si < nseg; si++) {
    int qt, k0, k1, mode;                      // mode: 0 owned, 1 ->PA, 2 ->PB
    if (isA && si == 0) { qt = pi;      k0 = 0;       k1 = pi + 1;  mode = 0; }
    else if (isA)       { qt = 63 - pi; k0 = 0;       k1 = 31 - pi; mode = 1; }
    else                { qt = 63 - pi; k0 = 31 - pi; k1 = 64 - pi; mode = 2; }

    // stage Q (64x256) -> Ks (syncthreads drains prior epilogue stores too)
    {
      const u16* Qg = qkv + (size_t)(qt * 64) * 4096 + h * 256;
#pragma unroll
      for (int s = 0; s < 8; s++) {
        int kr = (w * 8 + s) * 2 + hi;
        int klc = l31 ^ (kr & 31);
        load_lds16(Qg + (size_t)kr * 4096 + klc * 8, &Ks[(w * 8 + s) * 512]);
      }
    }
    __syncthreads();                           // Q staged (full drain)

    bf16x8 aq[16];                             // 32q x 256k A-frags
#pragma unroll
    for (int kc = 0; kc < 16; kc++)
      aq[kc] = *(const bf16x8*)&Ks[(qhalf * 32 + l31) * 256 +
                                   (((kc * 2 + hi) ^ l31) << 3)];
    __syncthreads();                           // aq reads done -> Ks reusable

    f32x16 ao[4];
#pragma unroll
    for (int g = 0; g < 4; g++) ao[g] = (f32x16)(0.f);
    f32x16 al = (f32x16)(0.f);

    for (int t = k0; t < k1; t++) {
      // stage tile t: 8 K loads FIRST, then 8 V loads (vmcnt(8) waits only
      // the 8 oldest = K; V flies across the S phase)
      {
        const u16* Kt = Kg + (size_t)(t * 64) * 4096;
        const u16* Vt = Vg0 + t * 64;
#pragma unroll
        for (int s = 0; s < 8; s++) {
          int kr = (w * 8 + s) * 2 + hi;
          int klc = l31 ^ (kr & 31);
          load_lds16(Kt + (size_t)kr * 4096 + klc * 8, &Ks[(w * 8 + s) * 512]);
        }
#pragma unroll
        for (int s = 0; s < 8; s++) {
          int vr = (w * 8 + s) * 8 + vro;
          load_lds16(Vt + (size_t)vr * 4096 + vlc * 8, &Vs[(w * 8 + s) * 512]);
        }
      }
      asm volatile("s_waitcnt vmcnt(8)" ::: "memory");
      BARX();

      // S quarter: 32q x 32k, 16 MFMA in TWO independent chains (ILP 2)
      f32x16 se = (f32x16)(0.f);
      f32x16 so = (f32x16)(0.f);
#pragma unroll
      for (int kc = 0; kc < 8; kc++) {
        bf16x8 bk0 = *(const bf16x8*)&Ks[(kh * 32 + l31) * 256 +
                                         ((((2 * kc) * 2 + hi) ^ l31) << 3)];
        se = __builtin_amdgcn_mfma_f32_32x32x16_bf16(aq[2 * kc], bk0, se, 0, 0, 0);
        bf16x8 bk1 = *(const bf16x8*)&Ks[(kh * 32 + l31) * 256 +
                                         ((((2 * kc + 1) * 2 + hi) ^ l31) << 3)];
        so = __builtin_amdgcn_mfma_f32_32x32x16_bf16(aq[2 * kc + 1], bk1, so, 0, 0, 0);
      }
      f32x16 sacc = se + so;

      // softcap -> P (bf16, swizzled shared LDS); mask only on diagonal tile
      bool diag = (t == qt);
#pragma unroll
      for (int reg = 0; reg < 16; reg++) {
        int qa = 4 * hi + 8 * (reg >> 2) + (reg & 3);   // local q in 0..31
        int q64 = qhalf * 32 + qa;
        int key64 = kh * 32 + l31;
        float x = sacc[reg] * 0.00125f;          // s*(1/16)/50
        float x2 = x * x;
        float th = x * (1.f + x2 * (-0.33333333f + x2 * 0.13333333f));
        float p = exp2f(72.134752f * (th - 1.f));  // exp(50*tanh - 50)
        if (diag && key64 > q64) p = 0.f;
        Pl[q64 * 64 + (((key64 >> 3) ^ (q64 & 7)) << 3) + (key64 & 7)] = f2bf(p);
      }
      // publish P AND land V (V had the whole S phase of flight -> ~free)
      asm volatile("s_waitcnt vmcnt(0) lgkmcnt(0)" ::: "memory");
      BARX();

      // PV: O[qhalf 32][dhalf 128] += P[32][64] * V[64][128]; l via ones
      bf16x8 ap[4];
#pragma unroll
      for (int kc = 0; kc < 4; kc++)
        ap[kc] = *(const bf16x8*)&Pl[(qhalf * 32 + l31) * 64 +
                                     (((kc * 2 + hi) ^ (l31 & 7)) << 3)];
#pragma unroll
      for (int g = 0; g < 4; g++) {
        int dd = dhalf * 128 + g * 32 + l31;
#pragma unroll
        for (int kc = 0; kc < 4; kc++) {
          bf16x8 bv = *(const bf16x8*)&Vs[dd * 64 +
                                          (((kc * 2 + hi) ^ (l31 & 7)) << 3)];
          ao[g] = __builtin_amdgcn_mfma_f32_32x32x16_bf16(ap[kc], bv, ao[g], 0, 0, 0);
        }
      }
#pragma unroll
      for (int kc = 0; kc < 4; kc++)
        al = __builtin_amdgcn_mfma_f32_32x32x16_bf16(ap[kc], ones, al, 0, 0, 0);

      __syncthreads();                         // all readers done -> buffers free
    }

    // epilogue by mode
    if (mode == 0) {
      float inv_l[16];
#pragma unroll
      for (int reg = 0; reg < 16; reg++) inv_l[reg] = 1.f / al[reg];
      int qs = qt * 64 + qhalf * 32;
#pragma unroll
      for (int g = 0; g < 4; g++) {
        int col = h * 256 + dhalf * 128 + g * 32 + l31;
#pragma unroll
        for (int reg = 0; reg < 16; reg++) {
          int row = qs + 4 * hi + 8 * (reg >> 2) + (reg & 3);
          attn[(size_t)row * 2048 + col] = f2bf(ao[g][reg] * inv_l[reg]);
        }
      }
    } else {
      float* Pbuf = (mode == 1) ? PA : PB;
#pragma unroll
      for (int g = 0; g < 4; g++) {
        int col = dhalf * 128 + g * 32 + l31;
#pragma unroll
        for (int reg = 0; reg < 16; reg++) {
          int row = qhalf * 32 + 4 * hi + 8 * (reg >> 2) + (reg & 3);
          Pbuf[((size_t)r * 64 + row) * 256 + col] = ao[g][reg];
        }
      }
      if (dhalf == 0 && l31 == 0) {            // lanes 0 & 32 of waves 0,2
        size_t lbase = (size_t)(r * 16 + (mode - 1)) * 2048 + 1536;
#pragma unroll
        for (int reg = 0; reg < 16; reg++) {
          int row = qhalf * 32 + 4 * hi + 8 * (reg >> 2) + (reg & 3);
          lbuf[lbase + row] = al[reg];
        }
      }
    }
  }
}

// ---------------- launch ----------------

extern "C" void kernel_launch(void* const* d_in, const int* in_sizes, int n_in,
                              void* d_out, int out_size, void* d_ws, size_t ws_size,
                              hipStream_t stream) {
  const float* hs = (const float*)d_in[0];
  // d_in[1] attention_mask: pure causal (window 4096 never binds at S=4096)
  // d_in[2] position_ids: arange -> row index
  const float* wq = (const float*)d_in[3];
  const float* wk = (const float*)d_in[4];
  const float* wv = (const float*)d_in[5];
  const float* wo = (const float*)d_in[6];
  float* out = (float*)d_out;

  char* ws = (char*)d_ws;
  u16* hsb    = (u16*)(ws);                      // 4096x2048 bf16
  u16* wqkvT  = (u16*)(ws + 16777216);           // 4096x2048 bf16
  u16* woT    = (u16*)(ws + 33554432);           // 2048x2048 bf16
  u16* qkv    = (u16*)(ws + 41943040);           // 4096x4096 bf16
  u16* vT     = (u16*)(ws + 75497472);           // 1024x4096 bf16
  u16* attn   = (u16*)(ws + 83886080);           // 4096x2048 bf16 (rows <2048 used)
  // flash-phase overlays (dead regions during/after flash):
  float* PA   = (float*)(ws);                    // over hsb   (16MB)
  float* PB   = (float*)(ws + 16777216);         // over wqkvT (16MB)
  float* lbuf = (float*)(ws + 41943040);         // qkv base; dead V cols

  prep1_kernel<<<11264, 256, 0, stream>>>(hs, hsb, wq, wk, wv, wo, wqkvT, woT);
  gemm_mn_kernel<<<dim3(32, 16), 512, 0, stream>>>(hsb, wqkvT, qkv, 4096, 4096, 2048);
  prep2_kernel<<<3072, 256, 0, stream>>>(qkv, vT);
  flash_kernel<<<512, 256, 0, stream>>>(qkv, vT, attn, PA, PB, lbuf);
  gemm_out_kernel<<<dim3(16, 32), 256, 0, stream>>>(attn, woT, out, PA, PB, lbuf,
                                                    4096, 2048, 2048);
}

// Round 11
// 447.002 us; speedup vs baseline: 1.1354x; 1.1354x over previous
//
#include <hip/hip_runtime.h>

// Gemma2 attention, S=4096 HID=2048 NH=8 NKV=4 HD=256, causal, tanh softcap 50,
// scaling 1/16. R16: revert to R14 (session best, 450.98us measured).
// R15's combine-fold into gemm2 regressed +56us: gemm2's A-panel is re-read
// by all 16 n-tile blocks, so deriving merged rows from f32 PA/PB partials
// per-block multiplied partial reads 16x (~512MB). combine materializes them
// ONCE -> kept as its own kernel. Config: prep1 (convert+4x transpose_w),
// gemm_mn (256x128 BK=32 ring-2, 2 blocks/CU), prep2 (rope 1-sincos +
// transpose_v), flash (R9 balanced 2-blocks/CU additive-partial split + R14
// split-stage vmcnt(8) K-first), combine, gemm2 (m97, f32 out).
// Remaining levers if further rounds: T12 swapped-QK^T flash rewrite
// (lane-local P, est -25-35us, high layout risk).

#define SEQ 4096
#define HIDDEN 2048
#define NHEADS 8
#define HDIM 256

typedef unsigned short u16;
typedef __attribute__((ext_vector_type(8))) __bf16 bf16x8;
typedef __attribute__((ext_vector_type(4))) float f32x4;
typedef __attribute__((ext_vector_type(16))) float f32x16;

static __device__ inline u16 f2bf(float f) {
  union { float f; unsigned u; } x; x.f = f;
  unsigned r = x.u + 0x7FFFu + ((x.u >> 16) & 1u);   // RNE
  return (u16)(r >> 16);
}
static __device__ inline float bf2f(u16 u) {
  union { unsigned u; float f; } x; x.u = ((unsigned)u) << 16;
  return x.f;
}

typedef __attribute__((address_space(1))) const unsigned int* gp_t;
typedef __attribute__((address_space(3))) unsigned int* lp_t;
static __device__ inline void load_lds16(const u16* g, u16* l) {
  __builtin_amdgcn_global_load_lds((gp_t)g, (lp_t)l, 16, 0, 0);
}

#define BARX() do { __builtin_amdgcn_s_barrier(); asm volatile("" ::: "memory"); } while (0)

// ---------------- prep1: convert_hs + 4x transpose_w fused ----------------

__global__ void prep1_kernel(const float* __restrict__ hs, u16* __restrict__ hsb,
                             const float* __restrict__ wq, const float* __restrict__ wk,
                             const float* __restrict__ wv, const float* __restrict__ wo,
                             u16* __restrict__ wqkvT, u16* __restrict__ woT) {
  __shared__ u16 tile[64][65];
  int bid = blockIdx.x, tid = threadIdx.x;
  if (bid < 8192) {                            // convert hs -> bf16
    int i = bid * 256 + tid;
    float4 v = ((const float4*)hs)[i];
    ushort4 o;
    o.x = f2bf(v.x); o.y = f2bf(v.y); o.z = f2bf(v.z); o.w = f2bf(v.w);
    ((ushort4*)hsb)[i] = o;
    return;
  }
  int tb = bid - 8192;
  const float* src; u16* dst; int N, n0, k0;
  if (tb < 1024)      { src = wq; dst = wqkvT;                        N = 2048; n0 = (tb & 31) * 64; k0 = (tb >> 5) * 64; }
  else if (tb < 1536) { int x = tb - 1024; src = wk; dst = wqkvT + (size_t)2048 * 2048; N = 1024; n0 = (x & 15) * 64; k0 = (x >> 4) * 64; }
  else if (tb < 2048) { int x = tb - 1536; src = wv; dst = wqkvT + (size_t)3072 * 2048; N = 1024; n0 = (x & 15) * 64; k0 = (x >> 4) * 64; }
  else                { int x = tb - 2048; src = wo; dst = woT;       N = 2048; n0 = (x & 31) * 64; k0 = (x >> 5) * 64; }
  const int K = 2048;
  for (int i = 0; i < 16; i++) {
    int idx = i * 256 + tid; int r = idx >> 6, c = idx & 63;
    tile[r][c] = f2bf(src[(size_t)(k0 + r) * N + n0 + c]);
  }
  __syncthreads();
  for (int i = 0; i < 16; i++) {
    int idx = i * 256 + tid; int r = idx >> 6, c = idx & 63;
    dst[(size_t)(n0 + r) * K + k0 + c] = tile[c][r];
  }
}

// ---------------- prep2: rope + transpose_v fused ----------------

__global__ void prep2_kernel(u16* __restrict__ qkv, u16* __restrict__ vT) {
  __shared__ u16 tile[64][65];
  int bid = blockIdx.x, tid = threadIdx.x;
  if (bid < 2048) {                            // rope: one sincos per (s,i)
    int idx = bid * 256 + tid;                 // 4096*128
    int s = idx >> 7;
    int i = idx & 127;
    float inv = __expf(-(float)i * 0.0719557841560639f);  // ln(10000)/128
    float ang = (float)s * inv;
    float sn, cs;
    sincosf(ang, &sn, &cs);
    size_t rowb = (size_t)s * 4096;
#pragma unroll
    for (int hh = 0; hh < 12; hh++) {
      size_t base = rowb + hh * 256 + i;
      float a = bf2f(qkv[base]);
      float b = bf2f(qkv[base + 128]);
      qkv[base]       = f2bf(a * cs - b * sn);
      qkv[base + 128] = f2bf(b * cs + a * sn);
    }
    return;
  }
  int x = bid - 2048;
  int d0 = (x & 15) * 64, s0 = (x >> 4) * 64;
  for (int i = 0; i < 16; i++) {
    int idx = i * 256 + tid; int r = idx >> 6, c = idx & 63;
    tile[r][c] = qkv[(size_t)(s0 + r) * 4096 + 3072 + d0 + c];
  }
  __syncthreads();
  for (int i = 0; i < 16; i++) {
    int idx = i * 256 + tid; int r = idx >> 6, c = idx & 63;
    vT[(size_t)(d0 + r) * 4096 + s0 + c] = tile[c][r];
  }
}

// ---------------- gemm1: 256x128 tile, BK=32, ring-2, 2 blocks/CU ----------------

__global__ __launch_bounds__(512, 4) void gemm_mn_kernel(
    const u16* __restrict__ A, const u16* __restrict__ Bt, u16* __restrict__ C,
    int M, int N, int K) {
  __shared__ __attribute__((aligned(16))) u16 As[2][256 * 32];
  __shared__ __attribute__((aligned(16))) u16 Bs[2][128 * 32];
  int tid = threadIdx.x;
  int wid = tid >> 6, lane = tid & 63;
  int lm = lane & 15, kq = lane >> 4;
  int wm = (wid >> 1) * 64, wn = (wid & 1) * 64;
  int m0 = blockIdx.y * 256, n0 = blockIdx.x * 128;
  int T = K >> 5;

  int r0 = tid >> 2, c0 = tid & 3;
  int csw = ((c0 ^ (r0 & 3)) << 3);
  const u16* gA0 = A  + (size_t)(m0 + r0) * K + csw;
  const u16* gA1 = A  + (size_t)(m0 + 128 + r0) * K + csw;
  const u16* gB0 = Bt + (size_t)(n0 + r0) * K + csw;

  f32x4 acc[4][4];
#pragma unroll
  for (int a = 0; a < 4; a++)
#pragma unroll
    for (int b = 0; b < 4; b++) acc[a][b] = (f32x4){0.f, 0.f, 0.f, 0.f};

  int xsw = ((kq ^ (lm & 3)) << 3);

  load_lds16(gA0, &As[0][tid * 8]);
  load_lds16(gA1, &As[0][(512 + tid) * 8]);
  load_lds16(gB0, &Bs[0][tid * 8]);
  asm volatile("s_waitcnt vmcnt(0)" ::: "memory");
  BARX();

  for (int t = 0; t < T; ++t) {
    int cur = t & 1;
    if (t + 1 < T) {
      int nb = 1 - cur;
      load_lds16(gA0 + (t + 1) * 32, &As[nb][tid * 8]);
      load_lds16(gA1 + (t + 1) * 32, &As[nb][(512 + tid) * 8]);
      load_lds16(gB0 + (t + 1) * 32, &Bs[nb][tid * 8]);
    }
    bf16x8 af[4], bfr[4];
#pragma unroll
    for (int f = 0; f < 4; f++)
      af[f] = *(const bf16x8*)&As[cur][(wm + f * 16 + lm) * 32 + xsw];
#pragma unroll
    for (int f = 0; f < 4; f++)
      bfr[f] = *(const bf16x8*)&Bs[cur][(wn + f * 16 + lm) * 32 + xsw];
    __builtin_amdgcn_s_setprio(1);
#pragma unroll
    for (int mi = 0; mi < 4; mi++)
#pragma unroll
      for (int ni = 0; ni < 4; ni++)
        acc[mi][ni] = __builtin_amdgcn_mfma_f32_16x16x32_bf16(af[mi], bfr[ni],
                                                             acc[mi][ni], 0, 0, 0);
    __builtin_amdgcn_s_setprio(0);
    if (t + 1 < T) {
      asm volatile("s_waitcnt vmcnt(0)" ::: "memory");
      BARX();
    }
  }

#pragma unroll
  for (int mi = 0; mi < 4; mi++) {
    int row = m0 + wm + mi * 16 + kq * 4;
#pragma unroll
    for (int ni = 0; ni < 4; ni++) {
      int col = n0 + wn + ni * 16 + lm;
#pragma unroll
      for (int r = 0; r < 4; r++)
        C[(size_t)(row + r) * N + col] = f2bf(acc[mi][ni][r]);
    }
  }
}

// ---------------- GEMM (m97 structure, gemm2) ----------------

template <bool OUT_F32>
__global__ __launch_bounds__(256, 2) void gemm_bf16_kernel(
    const u16* __restrict__ A, const u16* __restrict__ Bt, void* __restrict__ Cout,
    int M, int N, int K) {
  __shared__ __attribute__((aligned(16))) u16 As[128 * 64];
  __shared__ __attribute__((aligned(16))) u16 Bs[128 * 64];
  int tid = threadIdx.x;
  int wave = tid >> 6, lane = tid & 63;
  int lm = lane & 15, qd = lane >> 4;
  int m0 = blockIdx.y * 128, n0 = blockIdx.x * 128;
  int wm = (wave >> 1) * 64, wn = (wave & 1) * 64;

  f32x4 acc[4][4];
#pragma unroll
  for (int a = 0; a < 4; a++)
#pragma unroll
    for (int b = 0; b < 4; b++) acc[a][b] = (f32x4){0.f, 0.f, 0.f, 0.f};

  int srow = lane >> 3;
  int scol = (lane & 7) * 8;

  for (int kt = 0; kt < K; kt += 64) {
    __syncthreads();
#pragma unroll
    for (int t = 0; t < 4; t++) {
      int j = wave * 4 + t;
      int row = j * 8 + srow;
      load_lds16(A  + (size_t)(m0 + row) * K + kt + scol, As + j * 512);
      load_lds16(Bt + (size_t)(n0 + row) * K + kt + scol, Bs + j * 512);
    }
    __syncthreads();
#pragma unroll
    for (int kk = 0; kk < 2; kk++) {
      bf16x8 af[4], bfr[4];
#pragma unroll
      for (int mi = 0; mi < 4; mi++)
        af[mi] = *(const bf16x8*)&As[(wm + mi * 16 + lm) * 64 + kk * 32 + qd * 8];
#pragma unroll
      for (int ni = 0; ni < 4; ni++)
        bfr[ni] = *(const bf16x8*)&Bs[(wn + ni * 16 + lm) * 64 + kk * 32 + qd * 8];
#pragma unroll
      for (int mi = 0; mi < 4; mi++)
#pragma unroll
        for (int ni = 0; ni < 4; ni++)
          acc[mi][ni] = __builtin_amdgcn_mfma_f32_16x16x32_bf16(af[mi], bfr[ni],
                                                               acc[mi][ni], 0, 0, 0);
    }
  }
#pragma unroll
  for (int mi = 0; mi < 4; mi++) {
    int row = m0 + wm + mi * 16 + qd * 4;
#pragma unroll
    for (int ni = 0; ni < 4; ni++) {
      int col = n0 + wn + ni * 16 + lm;
#pragma unroll
      for (int r = 0; r < 4; r++) {
        float v = acc[mi][ni][r];
        if (OUT_F32) ((float*)Cout)[(size_t)(row + r) * N + col] = v;
        else         ((u16*)Cout)[(size_t)(row + r) * N + col] = f2bf(v);
      }
    }
  }
}

// ---------------- flash attention (R14: balanced 2 blocks/CU, split-stage vmcnt) ----------------

__global__ __launch_bounds__(256, 2) void flash_kernel(
    const u16* __restrict__ qkv, const u16* __restrict__ vT,
    u16* __restrict__ attn, float* __restrict__ PA, float* __restrict__ PB,
    float* __restrict__ lbuf /* == (float*)qkv base */) {
  __shared__ __attribute__((aligned(16))) u16 Ks[64 * 256];
  __shared__ __attribute__((aligned(16))) u16 Vs[256 * 64];
  __shared__ __attribute__((aligned(16))) u16 Pl[64 * 64];

  int tid = threadIdx.x;
  int w = tid >> 6, lane = tid & 63;
  int l31 = lane & 31, hi = lane >> 5;
  int qhalf = w >> 1, kh = w & 1, dhalf = w & 1;

  int b = blockIdx.x;            // 0..511
  int r = b & 255;
  int h = r & 7;                 // one head per XCD; same for b and b+256
  int pi = r >> 3;               // 0..31
  int kvh = h >> 1;
  int isA = (b < 256);
  int nseg = isA ? 2 : 1;

  int vlc = (lane & 7) ^ ((lane >> 3) & 7);    // V logical 16B chunk
  int vro = lane >> 3;                          // V row offset in 8-row window

  const u16* Kg  = qkv + 2048 + (size_t)kvh * 256;
  const u16* Vg0 = vT + (size_t)(kvh * 256) * 4096;

  bf16x8 ones;
#pragma unroll
  for (int e = 0; e < 8; e++) ones[e] = (__bf16)1.0f;

  for (int si = 0; si < nseg; si++) {
    int qt, k0, k1, mode;                      // mode: 0 owned, 1 ->PA, 2 ->PB
    if (isA && si == 0) { qt = pi;      k0 = 0;       k1 = pi + 1;  mode = 0; }
    else if (isA)       { qt = 63 - pi; k0 = 0;       k1 = 31 - pi; mode = 1; }
    else                { qt = 63 - pi; k0 = 31 - pi; k1 = 64 - pi; mode = 2; }

    // stage Q (64x256) -> Ks (syncthreads drains prior epilogue stores too)
    {
      const u16* Qg = qkv + (size_t)(qt * 64) * 4096 + h * 256;
#pragma unroll
      for (int s = 0; s < 8; s++) {
        int kr = (w * 8 + s) * 2 + hi;
        int klc = l31 ^ (kr & 31);
        load_lds16(Qg + (size_t)kr * 4096 + klc * 8, &Ks[(w * 8 + s) * 512]);
      }
    }
    __syncthreads();                           // Q staged (full drain)

    bf16x8 aq[16];                             // 32q x 256k A-frags
#pragma unroll
    for (int kc = 0; kc < 16; kc++)
      aq[kc] = *(const bf16x8*)&Ks[(qhalf * 32 + l31) * 256 +
                                   (((kc * 2 + hi) ^ l31) << 3)];
    __syncthreads();                           // aq reads done -> Ks reusable

    f32x16 ao[4];
#pragma unroll
    for (int g = 0; g < 4; g++) ao[g] = (f32x16)(0.f);
    f32x16 al = (f32x16)(0.f);

    for (int t = k0; t < k1; t++) {
      // stage tile t: 8 K loads FIRST, then 8 V loads (vmcnt(8) waits only
      // the 8 oldest = K; V flies across the S phase)
      {
        const u16* Kt = Kg + (size_t)(t * 64) * 4096;
        const u16* Vt = Vg0 + t * 64;
#pragma unroll
        for (int s = 0; s < 8; s++) {
          int kr = (w * 8 + s) * 2 + hi;
          int klc = l31 ^ (kr & 31);
          load_lds16(Kt + (size_t)kr * 4096 + klc * 8, &Ks[(w * 8 + s) * 512]);
        }
#pragma unroll
        for (int s = 0; s < 8; s++) {
          int vr = (w * 8 + s) * 8 + vro;
          load_lds16(Vt + (size_t)vr * 4096 + vlc * 8, &Vs[(w * 8 + s) * 512]);
        }
      }
      asm volatile("s_waitcnt vmcnt(8)" ::: "memory");
      BARX();

      // S quarter: 32q x 32k, 16 MFMA in TWO independent chains (ILP 2)
      f32x16 se = (f32x16)(0.f);
      f32x16 so = (f32x16)(0.f);
#pragma unroll
      for (int kc = 0; kc < 8; kc++) {
        bf16x8 bk0 = *(const bf16x8*)&Ks[(kh * 32 + l31) * 256 +
                                         ((((2 * kc) * 2 + hi) ^ l31) << 3)];
        se = __builtin_amdgcn_mfma_f32_32x32x16_bf16(aq[2 * kc], bk0, se, 0, 0, 0);
        bf16x8 bk1 = *(const bf16x8*)&Ks[(kh * 32 + l31) * 256 +
                                         ((((2 * kc + 1) * 2 + hi) ^ l31) << 3)];
        so = __builtin_amdgcn_mfma_f32_32x32x16_bf16(aq[2 * kc + 1], bk1, so, 0, 0, 0);
      }
      f32x16 sacc = se + so;

      // softcap -> P (bf16, swizzled shared LDS); mask only on diagonal tile
      bool diag = (t == qt);
#pragma unroll
      for (int reg = 0; reg < 16; reg++) {
        int qa = 4 * hi + 8 * (reg >> 2) + (reg & 3);   // local q in 0..31
        int q64 = qhalf * 32 + qa;
        int key64 = kh * 32 + l31;
        float x = sacc[reg] * 0.00125f;          // s*(1/16)/50
        float x2 = x * x;
        float th = x * (1.f + x2 * (-0.33333333f + x2 * 0.13333333f));
        float p = exp2f(72.134752f * (th - 1.f));  // exp(50*tanh - 50)
        if (diag && key64 > q64) p = 0.f;
        Pl[q64 * 64 + (((key64 >> 3) ^ (q64 & 7)) << 3) + (key64 & 7)] = f2bf(p);
      }
      // publish P AND land V (V had the whole S phase of flight -> ~free)
      asm volatile("s_waitcnt vmcnt(0) lgkmcnt(0)" ::: "memory");
      BARX();

      // PV: O[qhalf 32][dhalf 128] += P[32][64] * V[64][128]; l via ones
      bf16x8 ap[4];
#pragma unroll
      for (int kc = 0; kc < 4; kc++)
        ap[kc] = *(const bf16x8*)&Pl[(qhalf * 32 + l31) * 64 +
                                     (((kc * 2 + hi) ^ (l31 & 7)) << 3)];
#pragma unroll
      for (int g = 0; g < 4; g++) {
        int dd = dhalf * 128 + g * 32 + l31;
#pragma unroll
        for (int kc = 0; kc < 4; kc++) {
          bf16x8 bv = *(const bf16x8*)&Vs[dd * 64 +
                                          (((kc * 2 + hi) ^ (l31 & 7)) << 3)];
          ao[g] = __builtin_amdgcn_mfma_f32_32x32x16_bf16(ap[kc], bv, ao[g], 0, 0, 0);
        }
      }
#pragma unroll
      for (int kc = 0; kc < 4; kc++)
        al = __builtin_amdgcn_mfma_f32_32x32x16_bf16(ap[kc], ones, al, 0, 0, 0);

      __syncthreads();                         // all readers done -> buffers free
    }

    // epilogue by mode
    if (mode == 0) {
      float inv_l[16];
#pragma unroll
      for (int reg = 0; reg < 16; reg++) inv_l[reg] = 1.f / al[reg];
      int qs = qt * 64 + qhalf * 32;
#pragma unroll
      for (int g = 0; g < 4; g++) {
        int col = h * 256 + dhalf * 128 + g * 32 + l31;
#pragma unroll
        for (int reg = 0; reg < 16; reg++) {
          int row = qs + 4 * hi + 8 * (reg >> 2) + (reg & 3);
          attn[(size_t)row * 2048 + col] = f2bf(ao[g][reg] * inv_l[reg]);
        }
      }
    } else {
      float* Pbuf = (mode == 1) ? PA : PB;
#pragma unroll
      for (int g = 0; g < 4; g++) {
        int col = dhalf * 128 + g * 32 + l31;
#pragma unroll
        for (int reg = 0; reg < 16; reg++) {
          int row = qhalf * 32 + 4 * hi + 8 * (reg >> 2) + (reg & 3);
          Pbuf[((size_t)r * 64 + row) * 256 + col] = ao[g][reg];
        }
      }
      if (dhalf == 0 && l31 == 0) {            // lanes 0 & 32 of waves 0,2
        size_t lbase = (size_t)(r * 16 + (mode - 1)) * 2048 + 1536;
#pragma unroll
        for (int reg = 0; reg < 16; reg++) {
          int row = qhalf * 32 + 4 * hi + 8 * (reg >> 2) + (reg & 3);
          lbuf[lbase + row] = al[reg];
        }
      }
    }
  }
}

// combine: attn rows of qt2=63-pi (rows 2048..4095) = (PA+PB)/(lA+lB), bf16
__global__ __launch_bounds__(256) void combine_kernel(
    const float* __restrict__ PA, const float* __restrict__ PB,
    const float* __restrict__ lbuf, u16* __restrict__ attn) {
  int p = blockIdx.x;            // pair 0..255
  int h = p & 7, pi = p >> 3;
  int qt2 = 63 - pi;
  int tid = threadIdx.x;
  int row = tid >> 2;            // 0..63
  int c0 = (tid & 3) * 64;
  float la = lbuf[(size_t)(p * 16) * 2048 + 1536 + row];
  float lb = lbuf[(size_t)(p * 16 + 1) * 2048 + 1536 + row];
  float inv = 1.f / (la + lb);
  size_t src = ((size_t)p * 64 + row) * 256 + c0;
  size_t dst = (size_t)(qt2 * 64 + row) * 2048 + h * 256 + c0;
#pragma unroll
  for (int c = 0; c < 64; c += 4) {
    float4 a = *(const float4*)&PA[src + c];
    float4 bb = *(const float4*)&PB[src + c];
    ushort4 o;
    o.x = f2bf((a.x + bb.x) * inv);
    o.y = f2bf((a.y + bb.y) * inv);
    o.z = f2bf((a.z + bb.z) * inv);
    o.w = f2bf((a.w + bb.w) * inv);
    *(ushort4*)&attn[dst + c] = o;
  }
}

// ---------------- launch ----------------

extern "C" void kernel_launch(void* const* d_in, const int* in_sizes, int n_in,
                              void* d_out, int out_size, void* d_ws, size_t ws_size,
                              hipStream_t stream) {
  const float* hs = (const float*)d_in[0];
  // d_in[1] attention_mask: pure causal (window 4096 never binds at S=4096)
  // d_in[2] position_ids: arange -> row index
  const float* wq = (const float*)d_in[3];
  const float* wk = (const float*)d_in[4];
  const float* wv = (const float*)d_in[5];
  const float* wo = (const float*)d_in[6];
  float* out = (float*)d_out;

  char* ws = (char*)d_ws;
  u16* hsb    = (u16*)(ws);                      // 4096x2048 bf16
  u16* wqkvT  = (u16*)(ws + 16777216);           // 4096x2048 bf16
  u16* woT    = (u16*)(ws + 33554432);           // 2048x2048 bf16
  u16* qkv    = (u16*)(ws + 41943040);           // 4096x4096 bf16
  u16* vT     = (u16*)(ws + 75497472);           // 1024x4096 bf16
  u16* attn   = (u16*)(ws + 83886080);           // 4096x2048 bf16
  // flash-phase overlays (dead regions during/after flash):
  float* PA   = (float*)(ws);                    // over hsb   (16MB)
  float* PB   = (float*)(ws + 16777216);         // over wqkvT (16MB)
  float* lbuf = (float*)(ws + 41943040);         // qkv base; dead V cols

  prep1_kernel<<<11264, 256, 0, stream>>>(hs, hsb, wq, wk, wv, wo, wqkvT, woT);
  gemm_mn_kernel<<<dim3(32, 16), 512, 0, stream>>>(hsb, wqkvT, qkv, 4096, 4096, 2048);
  prep2_kernel<<<3072, 256, 0, stream>>>(qkv, vT);
  flash_kernel<<<512, 256, 0, stream>>>(qkv, vT, attn, PA, PB, lbuf);
  combine_kernel<<<256, 256, 0, stream>>>(PA, PB, lbuf, attn);
  gemm_bf16_kernel<true><<<dim3(16, 32), 256, 0, stream>>>(attn, woT, out, 4096, 2048, 2048);
}